// Round 9
// baseline (286.057 us; speedup 1.0000x reference)
//
#include <hip/hip_runtime.h>
#include <hip/hip_bf16.h>

typedef __bf16 bf16_t;
typedef __attribute__((ext_vector_type(8))) __bf16 bf16x8;
typedef __attribute__((ext_vector_type(4))) float f32x4;

#define KDIM 1152
#define NDIM 1152
#define BM 128
#define BN 192
#define BK 64
#define NIT 18                        /* K-steps of 64 */
#define NTILES 6                      /* 1152/192 */
#define SLAB_BYTES 12288              /* BN*32*2: one k-32 slab */
#define SLAB2_BYTES 24576             /* BK=64 step = 2 slabs */
#define TILE_BYTES (36 * SLAB_BYTES)  /* per n-tile panel */

__device__ __forceinline__ void gload_lds16(const void* g, void* l) {
    __builtin_amdgcn_global_load_lds(
        (const __attribute__((address_space(1))) void*)g,
        (__attribute__((address_space(3))) void*)l, 16, 0, 0);
}

template<int N> __device__ __forceinline__ void waitv() {
    if constexpr (N == 0)       asm volatile("s_waitcnt vmcnt(0)" ::: "memory");
    else if constexpr (N == 4)  asm volatile("s_waitcnt vmcnt(4)" ::: "memory");
    else if constexpr (N == 6)  asm volatile("s_waitcnt vmcnt(6)" ::: "memory");
    else if constexpr (N == 8)  asm volatile("s_waitcnt vmcnt(8)" ::: "memory");
    else if constexpr (N == 10) asm volatile("s_waitcnt vmcnt(10)" ::: "memory");
    if constexpr (N >= 0) __builtin_amdgcn_sched_barrier(0);
}
template<int N> __device__ __forceinline__ void waitv_lgkm() {
    if constexpr (N == 0)      asm volatile("s_waitcnt vmcnt(0) lgkmcnt(0)" ::: "memory");
    else if constexpr (N == 8) asm volatile("s_waitcnt vmcnt(8) lgkmcnt(0)" ::: "memory");
    if constexpr (N >= 0) __builtin_amdgcn_sched_barrier(0);
}
__device__ __forceinline__ void sinkf(float v) { asm volatile("" :: "v"(v)); }
__device__ __forceinline__ void sink8(bf16x8 v) {
    f32x4 u = __builtin_bit_cast(f32x4, v);
    asm volatile("" :: "v"(u[0]), "v"(u[1]), "v"(u[2]), "v"(u[3]));
}

// Weff panel, fragment-contiguous per n-tile (BN=192) — unchanged (proven).
__global__ void build_wb(const float* __restrict__ W,
                         const float* __restrict__ bvec,
                         bf16_t* __restrict__ Bm,
                         float* __restrict__ bias)
{
    const int t = blockIdx.x * blockDim.x + threadIdx.x;
    if (t < NDIM) {
        const int o = t / 9, p = t - o * 9;
        bias[t] = bvec[p * 128 + o];
    }
    const int c = t & 127;
    const int o = (t >> 7) & 127;
    const int p = t >> 14;
    if (p >= 9) return;
    const int r = p / 3, cc = p - r * 3;
    float eff[3][3] = {{0.f,0.f,0.f},{0.f,0.f,0.f},{0.f,0.f,0.f}};
    const float* w = W + (size_t)((p * 128 + o) * 128 + c) * 9;
    #pragma unroll
    for (int i = 0; i < 3; ++i) {
        const int a = (2 + r + i) / 3;
        #pragma unroll
        for (int j = 0; j < 3; ++j) {
            const int bb = (2 + cc + j) / 3;
            eff[a][bb] += w[i * 3 + j];
        }
    }
    const int n = o * 9 + p;
    const int tile = n / BN;
    const int nin = n - tile * BN;
    #pragma unroll
    for (int a = 0; a < 3; ++a)
        #pragma unroll
        for (int bb = 0; bb < 3; ++bb) {
            const int k = c * 9 + a * 3 + bb;
            const size_t idx = (size_t)tile * (TILE_BYTES / 2)
                             + (k >> 5) * (SLAB_BYTES / 2)
                             + (nin >> 4) * 512 + ((k >> 3) & 3) * 128
                             + (nin & 15) * 8 + (k & 7);
            Bm[idx] = (bf16_t)eff[a][bb];
        }
}

// ABLATION PROBE (body = round-6 kernel, the 90 µs best).
// MODE 0: real (stores out).          MODE 1: full compute, sink epilogue.
// MODE 2: no MFMA (sink af/bfr).      MODE 3: no B staging (LDS uninit).
// MODE 4: no A loads (const af).
// vmcnt counts re-derived per mode so waits stay exact.
template<int MODE>
__launch_bounds__(256, 3)
__global__ void gemm_probe(const float* __restrict__ X,
                           const bf16_t* __restrict__ Bm,
                           const float* __restrict__ bias,
                           float* __restrict__ out)
{
    constexpr bool HAS_B  = (MODE != 3);
    constexpr bool HAS_A  = (MODE != 4);
    constexpr int WP = HAS_B ? (HAS_A ? 8 : 0) : -1;   // prologue drain B(0)
    constexpr int W1 = HAS_A ? (HAS_B ? 10 : 4) : -1;  // drain A(t) kk0
    constexpr int W2 = HAS_A ? (HAS_B ? 6 : 0) : -1;   // drain A(t) kk1
    constexpr int W3 = HAS_B ? (HAS_A ? 8 : 0) : -1;   // drain B(t+1)
    constexpr int WT1 = HAS_A ? 4 : -1;                // tail kk0
    constexpr int WT2 = HAS_A ? 0 : -1;                // tail kk1

    __shared__ char Bs[2][SLAB2_BYTES];

    const int tid = threadIdx.x;
    const int lane = tid & 63;
    const int w = tid >> 6;

    const int bid = blockIdx.x;
    const int swz = (bid & 7) * 96 + (bid >> 3);
    const int mt = swz / NTILES;
    const int nt = swz - mt * NTILES;
    const int m0 = mt * BM;

    const float* abase = X + (size_t)(m0 + w * 32 + (lane & 15)) * KDIM
                           + ((lane >> 4) * 8);
    const char* bpanel = (const char*)Bm + (size_t)nt * TILE_BYTES;
    const int fr = (lane >> 4) * 256 + (lane & 15) * 16;

    f32x4 acc[2][12];
    #pragma unroll
    for (int i = 0; i < 2; ++i)
        #pragma unroll
        for (int j = 0; j < 12; ++j)
            acc[i][j] = (f32x4){0.f, 0.f, 0.f, 0.f};

    f32x4 ra0[2][2], ra1[2][2];
    bf16x8 af0[2], af1[2];
    if constexpr (!HAS_A) {
        #pragma unroll
        for (int mi = 0; mi < 2; ++mi)
            #pragma unroll
            for (int j = 0; j < 8; ++j) { af0[mi][j] = (__bf16)1.0f; af1[mi][j] = (__bf16)1.0f; }
    }

    #define LOADA(KT) do {                                                  \
        _Pragma("unroll")                                                   \
        for (int mi = 0; mi < 2; ++mi) {                                    \
            const float* p_ = abase + (size_t)mi * 16 * KDIM + (KT) * BK;   \
            asm volatile("global_load_dwordx4 %0, %2, off\n\t"              \
                         "global_load_dwordx4 %1, %2, off offset:16"        \
                         : "=&v"(ra0[mi][0]), "=&v"(ra0[mi][1])             \
                         : "v"(p_) : "memory");                             \
        }                                                                   \
        _Pragma("unroll")                                                   \
        for (int mi = 0; mi < 2; ++mi) {                                    \
            const float* p_ = abase + (size_t)mi * 16 * KDIM + (KT) * BK + 32; \
            asm volatile("global_load_dwordx4 %0, %2, off\n\t"              \
                         "global_load_dwordx4 %1, %2, off offset:16"        \
                         : "=&v"(ra1[mi][0]), "=&v"(ra1[mi][1])             \
                         : "v"(p_) : "memory");                             \
        } } while (0)

    #define GLDB(KT, BUF) do {                                              \
        const char* src_ = bpanel + (size_t)(KT) * SLAB2_BYTES;             \
        _Pragma("unroll")                                                   \
        for (int r_ = 0; r_ < 6; ++r_) {                                    \
            const int u_ = (tid + r_ * 256) * 16;                           \
            gload_lds16(src_ + u_, &Bs[BUF][u_]);                           \
        } } while (0)

    #define CVT(AF, RA) do {                                                \
        _Pragma("unroll")                                                   \
        for (int mi = 0; mi < 2; ++mi) {                                    \
            bf16x8 v_;                                                      \
            _Pragma("unroll")                                               \
            for (int j_ = 0; j_ < 4; ++j_) {                                \
                v_[j_]     = (__bf16)RA[mi][0][j_];                         \
                v_[4 + j_] = (__bf16)RA[mi][1][j_];                         \
            }                                                               \
            AF[mi] = v_;                                                    \
        } } while (0)

    #define COMPUTE(BUF, KK, AF) do {                                       \
        const char* Bb_ = &Bs[BUF][(KK) * SLAB_BYTES];                      \
        __builtin_amdgcn_s_setprio(1);                                      \
        _Pragma("unroll")                                                   \
        for (int c_ = 0; c_ < 4; ++c_) {                                    \
            bf16x8 bfr_[3];                                                 \
            _Pragma("unroll")                                               \
            for (int j_ = 0; j_ < 3; ++j_)                                  \
                bfr_[j_] = *(const bf16x8*)(Bb_ + (c_ * 3 + j_) * 1024 + fr); \
            if constexpr (MODE == 2) {                                      \
                sink8(AF[0]); sink8(AF[1]);                                 \
                sink8(bfr_[0]); sink8(bfr_[1]); sink8(bfr_[2]);             \
            } else {                                                        \
                _Pragma("unroll")                                           \
                for (int mi = 0; mi < 2; ++mi)                              \
                    _Pragma("unroll")                                       \
                    for (int j_ = 0; j_ < 3; ++j_)                          \
                        acc[mi][c_ * 3 + j_] = __builtin_amdgcn_mfma_f32_16x16x32_bf16( \
                            AF[mi], bfr_[j_], acc[mi][c_ * 3 + j_], 0, 0, 0); \
            }                                                               \
        }                                                                   \
        __builtin_amdgcn_s_setprio(0);                                      \
    } while (0)

    // ---- prologue ----
    if constexpr (HAS_B) GLDB(0, 0);
    if constexpr (HAS_A) LOADA(0);
    waitv<WP>();
    __builtin_amdgcn_s_barrier();

    #pragma unroll 1
    for (int t = 0; t < NIT - 1; ++t) {
        const int buf = t & 1;
        if constexpr (HAS_B) GLDB(t + 1, buf ^ 1);
        waitv<W1>();
        if constexpr (HAS_A) CVT(af0, ra0);
        COMPUTE(buf, 0, af0);
        waitv<W2>();
        if constexpr (HAS_A) { CVT(af1, ra1); LOADA(t + 1); }
        COMPUTE(buf, 1, af1);
        waitv_lgkm<W3>();
        __builtin_amdgcn_s_barrier();
    }
    // ---- final K-step (t = 17, buf = 1) ----
    waitv<WT1>();
    if constexpr (HAS_A) CVT(af0, ra0);
    COMPUTE(1, 0, af0);
    waitv<WT2>();
    if constexpr (HAS_A) CVT(af1, ra1);
    COMPUTE(1, 1, af1);

    #undef LOADA
    #undef GLDB
    #undef CVT
    #undef COMPUTE

    // ---- epilogue ----
    if constexpr (MODE == 0) {
        const int orow = (lane >> 4) * 4;
        const int ocol = lane & 15;
        const int gn0 = nt * BN + ocol;
        #pragma unroll
        for (int ni = 0; ni < 12; ++ni) {
            const float bv = bias[gn0 + ni * 16];
            #pragma unroll
            for (int mi = 0; mi < 2; ++mi) {
                float* po = out + (size_t)(m0 + w * 32 + mi * 16 + orow) * NDIM
                                + gn0 + ni * 16;
                #pragma unroll
                for (int r = 0; r < 4; ++r)
                    po[(size_t)r * NDIM] = acc[mi][ni][r] + bv;
            }
        }
    } else {
        float s = 0.f;
        #pragma unroll
        for (int mi = 0; mi < 2; ++mi)
            #pragma unroll
            for (int ni = 0; ni < 12; ++ni)
                #pragma unroll
                for (int r = 0; r < 4; ++r)
                    s += acc[mi][ni][r];
        sinkf(s);
    }
}

extern "C" void kernel_launch(void* const* d_in, const int* in_sizes, int n_in,
                              void* d_out, int out_size, void* d_ws, size_t ws_size,
                              hipStream_t stream)
{
    const float* x  = (const float*)d_in[0];
    const float* W  = (const float*)d_in[1];
    const float* bv = (const float*)d_in[2];
    float* out = (float*)d_out;

    bf16_t* Bm  = (bf16_t*)d_ws;                              // 1152*1152 bf16 = 2.65 MB
    float* bias = (float*)((char*)d_ws + (size_t)KDIM * NDIM * sizeof(bf16_t));

    build_wb<<<576, 256, 0, stream>>>(W, bv, Bm, bias);
    // Ablation probes (no output writes; counters give per-dispatch dur):
    gemm_probe<1><<<768, 256, 0, stream>>>(x, Bm, bias, out);  // no stores
    gemm_probe<2><<<768, 256, 0, stream>>>(x, Bm, bias, out);  // no MFMA
    gemm_probe<3><<<768, 256, 0, stream>>>(x, Bm, bias, out);  // no B staging
    gemm_probe<4><<<768, 256, 0, stream>>>(x, Bm, bias, out);  // no A loads
    // Real kernel (round-6 structure), writes d_out:
    gemm_probe<0><<<768, 256, 0, stream>>>(x, Bm, bias, out);
}

// Round 11
// 106.056 us; speedup vs baseline: 2.6972x; 2.6972x over previous
//
#include <hip/hip_runtime.h>
#include <hip/hip_bf16.h>

typedef __bf16 bf16_t;
typedef __attribute__((ext_vector_type(8))) __bf16 bf16x8;
typedef __attribute__((ext_vector_type(4))) float f32x4;

#define KDIM 1152
#define NDIM 1152
#define BM 256
#define BN 288
#define BK 64
#define NIT 18                         /* K-steps of 64 */
#define NTILES 4                       /* 1152/288 */
#define SLAB_B 18432                   /* BN*32*2: one k-32 slab (bytes) */
#define SLAB2_B 36864                  /* BK=64 step = 2 slabs */
#define TILE_B (36 * SLAB_B)           /* 663552 B per n-tile panel */

__device__ __forceinline__ void gload_lds16(const void* g, void* l) {
    __builtin_amdgcn_global_load_lds(
        (const __attribute__((address_space(1))) void*)g,
        (__attribute__((address_space(3))) void*)l, 16, 0, 0);
}

// Weff panel, fragment-contiguous per n-tile (BN=288):
//   bf16 idx(n,k) = tile*331776 + (k>>5)*9216 + (nin>>4)*512 + ((k>>3)&3)*128
//                   + (nin&15)*8 + (k&7)    (tile = n/288, nin = n%288)
// => each K-64 step is a linear 36864B slab-pair; wave frag reads are 1KB
//    contiguous (conflict-free); gload_lds staging is linear.
__global__ void build_wb(const float* __restrict__ W,
                         const float* __restrict__ bvec,
                         bf16_t* __restrict__ Bm,
                         float* __restrict__ bias)
{
    const int t = blockIdx.x * blockDim.x + threadIdx.x;
    if (t < NDIM) {
        const int o = t / 9, p = t - o * 9;
        bias[t] = bvec[p * 128 + o];
    }
    const int c = t & 127;
    const int o = (t >> 7) & 127;
    const int p = t >> 14;
    if (p >= 9) return;
    const int r = p / 3, cc = p - r * 3;
    float eff[3][3] = {{0.f,0.f,0.f},{0.f,0.f,0.f},{0.f,0.f,0.f}};
    const float* w = W + (size_t)((p * 128 + o) * 128 + c) * 9;
    #pragma unroll
    for (int i = 0; i < 3; ++i) {
        const int a = (2 + r + i) / 3;
        #pragma unroll
        for (int j = 0; j < 3; ++j) {
            const int bb = (2 + cc + j) / 3;
            eff[a][bb] += w[i * 3 + j];
        }
    }
    const int n = o * 9 + p;
    const int tile = n / BN;
    const int nin = n - tile * BN;
    #pragma unroll
    for (int a = 0; a < 3; ++a)
        #pragma unroll
        for (int bb = 0; bb < 3; ++bb) {
            const int k = c * 9 + a * 3 + bb;
            const size_t idx = (size_t)tile * (TILE_B / 2)
                             + (k >> 5) * (SLAB_B / 2)
                             + (nin >> 4) * 512 + ((k >> 3) & 3) * 128
                             + (nin & 15) * 8 + (k & 7);
            Bm[idx] = (bf16_t)eff[a][bb];
        }
}

// 8-wave 4-phase GEMM: out[16384,1152] = X(fp32->bf16) * Weff(bf16) + bias.
// BM=256 x BN=288, grid 256 = exactly 1 block/CU (zero tail). 8 waves 4Mx2N,
// wave tile 64x144 (acc 4x9 = 144 VGPR). Per K-step: 4 phases, each
// {ds_read || stage-issue -> barrier -> lgkm0 -> setprio1 -> 18 MFMA ->
//  setprio0 -> barrier}. B: linear gload_lds (5/thr, dummy-padded uniform).
// A: reg-staged fp32->bf16, issue ph1 / cvt+ds_write ph3 (T14 split).
// A-LDS layout [kk][row][kgrp][16B]: wave frag read = contiguous 1KB
// (conflict-free; the 4096-stride group layout would be 4-way bank-aliased).
// One vmcnt(0)/K-step, ~2-3 phases of MFMA between issue and drain.
__launch_bounds__(512, 1)
__global__ void ind_gemm(const float* __restrict__ X,
                         const bf16_t* __restrict__ Bm,
                         const float* __restrict__ bias,
                         float* __restrict__ out)
{
    __shared__ char Ab[2][32768];   // [kk(2)][row(256)][kgrp(4)][16B]
    __shared__ char Bb[2][36864];   // 2 k-32 slabs, builder layout
    __shared__ char Scrap[1024];

    const int tid = threadIdx.x;
    const int lane = tid & 63;
    const int wid = tid >> 6;
    const int wm = wid >> 1;        // 0..3
    const int wn = wid & 1;         // 0..1

    // XCD swizzle: 256 blocks = 32/XCD; consecutive swz share an m-panel
    // across the 4 n-tiles (X reuse in that XCD's L2).
    const int bid = blockIdx.x;
    const int swz = (bid & 7) * 32 + (bid >> 3);
    const int mt = swz >> 2;
    const int nt = swz & 3;
    const int m0 = mt * BM;

    // A staging: thread owns half a row: row=tid>>1, k-half=(tid&1)*32
    const int arow = tid >> 1;
    const int akk = tid & 1;
    const float* agsrc = X + (size_t)(m0 + arow) * KDIM + akk * 32;

    const char* bpanel = (const char*)Bm + (size_t)nt * TILE_B;

    f32x4 acc[4][9];
    #pragma unroll
    for (int i = 0; i < 4; ++i)
        #pragma unroll
        for (int j = 0; j < 9; ++j)
            acc[i][j] = (f32x4){0.f, 0.f, 0.f, 0.f};

    f32x4 ra[8];
    bf16x8 af0, af1, af2, af3, bfr[9];

    #define LOADA(KT) do {                                                  \
        const float* p_ = agsrc + (size_t)(KT) * BK;                        \
        asm volatile("global_load_dwordx4 %0, %4, off\n\t"                  \
                     "global_load_dwordx4 %1, %4, off offset:16\n\t"        \
                     "global_load_dwordx4 %2, %4, off offset:32\n\t"        \
                     "global_load_dwordx4 %3, %4, off offset:48"            \
                     : "=&v"(ra[0]), "=&v"(ra[1]), "=&v"(ra[2]), "=&v"(ra[3]) \
                     : "v"(p_) : "memory");                                 \
        asm volatile("global_load_dwordx4 %0, %4, off offset:64\n\t"        \
                     "global_load_dwordx4 %1, %4, off offset:80\n\t"        \
                     "global_load_dwordx4 %2, %4, off offset:96\n\t"        \
                     "global_load_dwordx4 %3, %4, off offset:112"           \
                     : "=&v"(ra[4]), "=&v"(ra[5]), "=&v"(ra[6]), "=&v"(ra[7]) \
                     : "v"(p_) : "memory");                                 \
    } while (0)

    #define GLDB(KT, BUF) do {                                              \
        const char* src_ = bpanel + (size_t)(KT) * SLAB2_B;                 \
        _Pragma("unroll")                                                   \
        for (int r_ = 0; r_ < 4; ++r_) {                                    \
            const int u_ = (tid + r_ * 512) * 16;                           \
            gload_lds16(src_ + u_, &Bb[BUF][u_]);                           \
        }                                                                   \
        if (tid < 256) gload_lds16(src_ + (2048 + tid) * 16,                \
                                   &Bb[BUF][(2048 + tid) * 16]);            \
        else           gload_lds16(bpanel + (tid - 256) * 16, Scrap);       \
    } while (0)

    // Ab byte(kk,row,g) = kk*16384 + row*64 + g*16; thread writes 64B
    // contiguous; wave frag-read = 1KB contiguous (conflict-free).
    #define CVTWRITE(BUF) do {                                              \
        _Pragma("unroll")                                                   \
        for (int j_ = 0; j_ < 4; ++j_) {                                    \
            bf16x8 pk_;                                                     \
            _Pragma("unroll")                                               \
            for (int e_ = 0; e_ < 4; ++e_) {                                \
                pk_[e_]     = (__bf16)ra[2 * j_][e_];                       \
                pk_[4 + e_] = (__bf16)ra[2 * j_ + 1][e_];                   \
            }                                                               \
            *(bf16x8*)(&Ab[BUF][akk * 16384 + arow * 64 + j_ * 16]) = pk_;  \
        } } while (0)

    #define LDB(CUR, KK) do {                                               \
        _Pragma("unroll")                                                   \
        for (int j_ = 0; j_ < 9; ++j_)                                      \
            bfr[j_] = *(const bf16x8*)(&Bb[CUR][(KK) * SLAB_B               \
                        + (wn * 9 + j_) * 1024                              \
                        + (lane >> 4) * 256 + (lane & 15) * 16]);           \
    } while (0)

    #define LDA1(DST, CUR, KK, MI)                                          \
        DST = *(const bf16x8*)(&Ab[CUR][(KK) * 16384                        \
                + (wm * 64 + (MI) * 16 + (lane & 15)) * 64                  \
                + (lane >> 4) * 16])

    #define MM(AF, MI) do {                                                 \
        _Pragma("unroll")                                                   \
        for (int j_ = 0; j_ < 9; ++j_)                                      \
            acc[MI][j_] = __builtin_amdgcn_mfma_f32_16x16x32_bf16(          \
                AF, bfr[j_], acc[MI][j_], 0, 0, 0);                         \
    } while (0)

    #define BAR()   __builtin_amdgcn_s_barrier()
    #define LGKM0() do { asm volatile("s_waitcnt lgkmcnt(0)" ::: "memory"); \
                         __builtin_amdgcn_sched_barrier(0); } while (0)
    #define VM0()   do { asm volatile("s_waitcnt vmcnt(0)" ::: "memory");   \
                         __builtin_amdgcn_sched_barrier(0); } while (0)

    // ---- prologue: stage A(0),B(0) into buf 0 ----
    GLDB(0, 0);
    LOADA(0);
    VM0();
    CVTWRITE(0);
    LGKM0();
    BAR();

    #pragma unroll 1
    for (int t = 0; t < NIT - 1; ++t) {
        const int cur = t & 1;
        const int nxt = cur ^ 1;
        // ---- phase 0: kk0, mi 0-1 ----
        LDB(cur, 0);
        LDA1(af0, cur, 0, 0); LDA1(af1, cur, 0, 1);
        GLDB(t + 1, nxt);
        BAR(); LGKM0();
        __builtin_amdgcn_s_setprio(1); MM(af0, 0); MM(af1, 1);
        __builtin_amdgcn_s_setprio(0);
        BAR();
        // ---- phase 1: kk0, mi 2-3 ----
        LDA1(af2, cur, 0, 2); LDA1(af3, cur, 0, 3);
        LOADA(t + 1);
        BAR(); LGKM0();
        __builtin_amdgcn_s_setprio(1); MM(af2, 2); MM(af3, 3);
        __builtin_amdgcn_s_setprio(0);
        BAR();
        // ---- phase 2: kk1, mi 0-1 ----
        LDB(cur, 1);
        LDA1(af0, cur, 1, 0); LDA1(af1, cur, 1, 1);
        BAR(); LGKM0();
        __builtin_amdgcn_s_setprio(1); MM(af0, 0); MM(af1, 1);
        __builtin_amdgcn_s_setprio(0);
        BAR();
        // ---- phase 3: kk1, mi 2-3; drain + stage-write A(t+1) ----
        LDA1(af2, cur, 1, 2); LDA1(af3, cur, 1, 3);
        BAR(); LGKM0();
        __builtin_amdgcn_s_setprio(1); MM(af2, 2); MM(af3, 3);
        __builtin_amdgcn_s_setprio(0);
        VM0();
        CVTWRITE(nxt);
        LGKM0();
        BAR();
    }

    // ---- final K-step (t = 17, cur = 1): compute-only ----
    {
        const int cur = 1;
        LDB(cur, 0);
        LDA1(af0, cur, 0, 0); LDA1(af1, cur, 0, 1);
        BAR(); LGKM0();
        MM(af0, 0); MM(af1, 1);
        BAR();
        LDA1(af2, cur, 0, 2); LDA1(af3, cur, 0, 3);
        BAR(); LGKM0();
        MM(af2, 2); MM(af3, 3);
        BAR();
        LDB(cur, 1);
        LDA1(af0, cur, 1, 0); LDA1(af1, cur, 1, 1);
        BAR(); LGKM0();
        MM(af0, 0); MM(af1, 1);
        BAR();
        LDA1(af2, cur, 1, 2); LDA1(af3, cur, 1, 3);
        LGKM0();
        MM(af2, 2); MM(af3, 3);
    }

    #undef LOADA
    #undef GLDB
    #undef CVTWRITE
    #undef LDB
    #undef LDA1
    #undef MM
    #undef BAR
    #undef LGKM0
    #undef VM0

    // ---- epilogue: C/D col=lane&15, row=(lane>>4)*4+reg ----
    const int orow = (lane >> 4) * 4;
    const int ocol = lane & 15;
    const int gn0 = nt * BN + wn * 144 + ocol;
    #pragma unroll
    for (int ni = 0; ni < 9; ++ni) {
        const float bv = bias[gn0 + ni * 16];
        #pragma unroll
        for (int mi = 0; mi < 4; ++mi) {
            float* po = out + (size_t)(m0 + wm * 64 + mi * 16 + orow) * NDIM
                            + gn0 + ni * 16;
            #pragma unroll
            for (int r = 0; r < 4; ++r)
                po[(size_t)r * NDIM] = acc[mi][ni][r] + bv;
        }
    }
}

extern "C" void kernel_launch(void* const* d_in, const int* in_sizes, int n_in,
                              void* d_out, int out_size, void* d_ws, size_t ws_size,
                              hipStream_t stream)
{
    const float* x  = (const float*)d_in[0];
    const float* W  = (const float*)d_in[1];
    const float* bv = (const float*)d_in[2];
    float* out = (float*)d_out;

    bf16_t* Bm  = (bf16_t*)d_ws;                              // 1152*1152 bf16 = 2.65 MB
    float* bias = (float*)((char*)d_ws + (size_t)KDIM * NDIM * sizeof(bf16_t));

    build_wb<<<576, 256, 0, stream>>>(W, bv, Bm, bias);
    ind_gemm<<<256, 512, 0, stream>>>(x, Bm, bias, out);
}

// Round 13
// 89.443 us; speedup vs baseline: 3.1982x; 1.1857x over previous
//
#include <hip/hip_runtime.h>
#include <hip/hip_bf16.h>

typedef __bf16 bf16_t;
typedef __attribute__((ext_vector_type(8))) __bf16 bf16x8;
typedef __attribute__((ext_vector_type(4))) float f32x4;

#define KDIM 1152
#define NDIM 1152
#define BM 128
#define BN 192
#define BK 32
#define NIT 36                        /* K-steps of 32 */
#define NTILES 6                      /* 1152/192 */
#define A_STEP 8192                   /* BM*BK*2 bytes per (panel,ktile) */
#define A_PANEL 294912                /* BM*KDIM*2 bytes per m-panel */
#define B_STEP 12288                  /* BN*BK*2 bytes per ktile */
#define B_TILE (36 * B_STEP)          /* per n-tile panel */

__device__ __forceinline__ void gload_lds16(const void* g, void* l) {
    __builtin_amdgcn_global_load_lds(
        (const __attribute__((address_space(1))) void*)g,
        (__attribute__((address_space(3))) void*)l, 16, 0, 0);
}

// X fp32 -> bf16, pre-swizzled to the GEMM's A-fragment order:
//   16B unit u = P*18432 + T*512 + rb*64 + g*16 + r0
//   holds rows m=P*128+rb*16+r0, k=T*32+g*8 .. +7.
// GEMM stages (P,T) 8KB linearly; wave frag read = contiguous 1KB.
__global__ void cvt_x(const float* __restrict__ X, bf16_t* __restrict__ Xb)
{
    const int u = blockIdx.x * 256 + threadIdx.x;          // < 2359296
    const int w = u >> 9;
    const int P = w / 36;
    const int T = w - P * 36;
    const int rem = u & 511;
    const int rb = rem >> 6;
    const int g = (rem >> 4) & 3;
    const int r0 = rem & 15;
    const int m = P * 128 + rb * 16 + r0;
    const int k = T * 32 + g * 8;
    const float* src = X + (size_t)m * KDIM + k;
    f32x4 lo = *(const f32x4*)src;
    f32x4 hi = *(const f32x4*)(src + 4);
    bf16x8 v;
    #pragma unroll
    for (int e = 0; e < 4; ++e) { v[e] = (__bf16)lo[e]; v[4 + e] = (__bf16)hi[e]; }
    *(bf16x8*)((char*)Xb + (size_t)u * 16) = v;
}

// Weff panel, fragment-contiguous per n-tile (BN=192) — unchanged (proven):
//   bf16 idx(n,k) = tile*221184 + (k>>5)*6144 + (nin>>4)*512 + ((k>>3)&3)*128
//                   + (nin&15)*8 + (k&7)
__global__ void build_wb(const float* __restrict__ W,
                         const float* __restrict__ bvec,
                         bf16_t* __restrict__ Bm,
                         float* __restrict__ bias)
{
    const int t = blockIdx.x * blockDim.x + threadIdx.x;
    if (t < NDIM) {
        const int o = t / 9, p = t - o * 9;
        bias[t] = bvec[p * 128 + o];
    }
    const int c = t & 127;
    const int o = (t >> 7) & 127;
    const int p = t >> 14;
    if (p >= 9) return;
    const int r = p / 3, cc = p - r * 3;
    float eff[3][3] = {{0.f,0.f,0.f},{0.f,0.f,0.f},{0.f,0.f,0.f}};
    const float* w = W + (size_t)((p * 128 + o) * 128 + c) * 9;
    #pragma unroll
    for (int i = 0; i < 3; ++i) {
        const int a = (2 + r + i) / 3;
        #pragma unroll
        for (int j = 0; j < 3; ++j) {
            const int bb = (2 + cc + j) / 3;
            eff[a][bb] += w[i * 3 + j];
        }
    }
    const int n = o * 9 + p;
    const int tile = n / BN;
    const int nin = n - tile * BN;
    #pragma unroll
    for (int a = 0; a < 3; ++a)
        #pragma unroll
        for (int bb = 0; bb < 3; ++bb) {
            const int k = c * 9 + a * 3 + bb;
            const size_t idx = (size_t)tile * (B_TILE / 2)
                             + (k >> 5) * (B_STEP / 2)
                             + (nin >> 4) * 512 + ((k >> 3) & 3) * 128
                             + (nin & 15) * 8 + (k & 7);
            Bm[idx] = (bf16_t)eff[a][bb];
        }
}

// out[16384,1152] = Xb(bf16, pre-swizzled) * Weff(bf16) + bias.
// BM=128 x BN=192, BK=32, 4 waves (2m x 2n, wave 64x96, acc 4x6 = 96 VGPR).
// BOTH operands: linear gload_lds (A 2/thr + B 3/thr per step), dbuf,
// counted vmcnt (stage t+2 in flight across iters; drained to 0 only at the
// tail). No CVT, no A-regs, no ds_write in the loop.
// All frag reads = contiguous 1KB per wave (conflict-free, proven pattern).
// Grid 768 = exactly 3 blocks/CU; LDS 40KB -> 120KB/CU.
__launch_bounds__(256, 3)
__global__ void ind_gemm(const bf16_t* __restrict__ Xb,
                         const bf16_t* __restrict__ Bm,
                         const float* __restrict__ bias,
                         float* __restrict__ out)
{
    __shared__ char As[2][A_STEP];
    __shared__ char Bs[2][B_STEP];

    const int tid = threadIdx.x;
    const int lane = tid & 63;
    const int wid = tid >> 6;
    const int wm = wid >> 1;        // 0..1
    const int wn = wid & 1;         // 0..1

    // XCD swizzle: 768 blocks = 96/XCD; consecutive swz share an m-panel
    // (147KB bf16 -> L2-resident) across the 6 n-tiles.
    const int bid = blockIdx.x;
    const int swz = (bid & 7) * 96 + (bid >> 3);
    const int mt = swz / NTILES;
    const int nt = swz - mt * NTILES;
    const int m0 = mt * BM;

    const char* apanel = (const char*)Xb + (size_t)mt * A_PANEL;
    const char* bpanel = (const char*)Bm + (size_t)nt * B_TILE;
    const int fr = (lane >> 4) * 256 + (lane & 15) * 16;

    f32x4 acc[4][6];
    #pragma unroll
    for (int i = 0; i < 4; ++i)
        #pragma unroll
        for (int j = 0; j < 6; ++j)
            acc[i][j] = (f32x4){0.f, 0.f, 0.f, 0.f};

    #define GLDA(T, BUF) do {                                               \
        const char* s_ = apanel + (size_t)(T) * A_STEP;                     \
        gload_lds16(s_ + tid * 16,        &As[BUF][tid * 16]);              \
        gload_lds16(s_ + 4096 + tid * 16, &As[BUF][4096 + tid * 16]);       \
    } while (0)

    #define GLDB(T, BUF) do {                                               \
        const char* s_ = bpanel + (size_t)(T) * B_STEP;                     \
        _Pragma("unroll")                                                   \
        for (int r_ = 0; r_ < 3; ++r_) {                                    \
            const int u_ = (tid + r_ * 256) * 16;                           \
            gload_lds16(s_ + u_, &Bs[BUF][u_]);                             \
        } } while (0)

    // ---- prologue: stage t=0,1 into both buffers (10 loads/thread) ----
    GLDA(0, 0); GLDB(0, 0);
    GLDA(1, 1); GLDB(1, 1);
    asm volatile("s_waitcnt vmcnt(5)" ::: "memory");   // t0 complete; t1 flying
    __builtin_amdgcn_sched_barrier(0);
    __builtin_amdgcn_s_barrier();

    #pragma unroll 1
    for (int t = 0; t < NIT; ++t) {
        const int cur = t & 1;
        // frag reads (10 x ds_read_b128, all contiguous-1KB)
        bf16x8 af[4], bfr[6];
        #pragma unroll
        for (int mi = 0; mi < 4; ++mi)
            af[mi] = *(const bf16x8*)(&As[cur][(wm * 4 + mi) * 1024 + fr]);
        #pragma unroll
        for (int j = 0; j < 6; ++j)
            bfr[j] = *(const bf16x8*)(&Bs[cur][(wn * 6 + j) * 1024 + fr]);
        asm volatile("s_waitcnt lgkmcnt(0)" ::: "memory");
        __builtin_amdgcn_sched_barrier(0);
        __builtin_amdgcn_s_barrier();            // all waves done reading buf[cur]
        if (t < NIT - 2) {                       // stage t+2 into buf[cur]
            GLDA(t + 2, cur);
            GLDB(t + 2, cur);
        }
        __builtin_amdgcn_s_setprio(1);
        #pragma unroll
        for (int mi = 0; mi < 4; ++mi)
            #pragma unroll
            for (int j = 0; j < 6; ++j)
                acc[mi][j] = __builtin_amdgcn_mfma_f32_16x16x32_bf16(
                    af[mi], bfr[j], acc[mi][j], 0, 0, 0);
        __builtin_amdgcn_s_setprio(0);
        if (t < NIT - 2) {
            asm volatile("s_waitcnt vmcnt(5)" ::: "memory");   // buf[t+1] ready
            __builtin_amdgcn_sched_barrier(0);
        } else if (t == NIT - 2) {
            asm volatile("s_waitcnt vmcnt(0)" ::: "memory");
            __builtin_amdgcn_sched_barrier(0);
        }
        if (t < NIT - 1) __builtin_amdgcn_s_barrier();
    }

    #undef GLDA
    #undef GLDB

    // ---- epilogue: C/D col=lane&15, row=(lane>>4)*4+reg ----
    const int orow = (lane >> 4) * 4;
    const int ocol = lane & 15;
    const int gn0 = nt * BN + wn * 96 + ocol;
    #pragma unroll
    for (int ni = 0; ni < 6; ++ni) {
        const float bv = bias[gn0 + ni * 16];
        #pragma unroll
        for (int mi = 0; mi < 4; ++mi) {
            float* po = out + (size_t)(m0 + wm * 64 + mi * 16 + orow) * NDIM
                            + gn0 + ni * 16;
            #pragma unroll
            for (int r = 0; r < 4; ++r)
                po[(size_t)r * NDIM] = acc[mi][ni][r] + bv;
        }
    }
}

extern "C" void kernel_launch(void* const* d_in, const int* in_sizes, int n_in,
                              void* d_out, int out_size, void* d_ws, size_t ws_size,
                              hipStream_t stream)
{
    const float* x  = (const float*)d_in[0];
    const float* W  = (const float*)d_in[1];
    const float* bv = (const float*)d_in[2];
    float* out = (float*)d_out;

    // ws: Xb 37.75 MB | Bm 2.65 MB | bias 4.6 KB
    bf16_t* Xb   = (bf16_t*)d_ws;
    bf16_t* Bm   = (bf16_t*)((char*)d_ws + (size_t)16384 * KDIM * sizeof(bf16_t));
    float*  bias = (float*)((char*)Bm + (size_t)KDIM * NDIM * sizeof(bf16_t));

    cvt_x<<<9216, 256, 0, stream>>>(x, Xb);
    build_wb<<<576, 256, 0, stream>>>(W, bv, Bm, bias);
    ind_gemm<<<768, 256, 0, stream>>>(Xb, Bm, bias, out);
}